// Round 1
// baseline (484.586 us; speedup 1.0000x reference)
//
#include <hip/hip_runtime.h>
#include <hip/hip_bf16.h>

#define SEQ   4096
#define BATCH 32
#define HID   512
#define MTOT  (SEQ * BATCH)   // 131072

typedef float  f32x4  __attribute__((ext_vector_type(4)));
typedef __bf16 bf16x8 __attribute__((ext_vector_type(8)));
typedef unsigned short ushort8v __attribute__((ext_vector_type(8)));

__device__ __forceinline__ unsigned short f2bf(float f) {
    unsigned int u = __builtin_bit_cast(unsigned int, f);
    u = (u + 0x7fffu + ((u >> 16) & 1u)) >> 16;   // RNE
    return (unsigned short)u;
}

__device__ __forceinline__ float tanh_fast(float x) {
    float ax = fabsf(x);
    float e  = __expf(-2.0f * ax);           // in (0,1]
    float t  = (1.0f - e) * __builtin_amdgcn_rcpf(1.0f + e);
    return copysignf(t, x);
}

// ---- kernel 1: W fp32 -> bf16 ------------------------------------------
__global__ __launch_bounds__(256) void cvt_w_kernel(const float* __restrict__ W,
                                                    unsigned short* __restrict__ Wb) {
    int i = (blockIdx.x * 256 + threadIdx.x) * 4;
    float4 f = *(const float4*)(W + i);
    ushort4 u;
    u.x = f2bf(f.x); u.y = f2bf(f.y); u.z = f2bf(f.z); u.w = f2bf(f.w);
    *(ushort4*)(Wb + i) = u;
}

// ---- kernel 2: fused GEMM + tanh + ctx-dot -> sims ---------------------
// y[m,o] = sum_k x[m,k]*W[o,k];  sims[m] += sum_o ctx[o]*tanh(y+bias[o])
#define BM 128
#define BN 128
#define BK 64
#define LDSP 72   // padded LDS stride (bf16 elems); 144 B = 9*16 B

__global__ __launch_bounds__(256) void gemm_sim_kernel(
    const float* __restrict__ x, const unsigned short* __restrict__ Wb,
    const float* __restrict__ bias, const float* __restrict__ ctx,
    float* __restrict__ sims)
{
    __shared__ unsigned short As[BM][LDSP];
    __shared__ unsigned short Bs[BN][LDSP];

    const int nt = blockIdx.x;          // 0..3  (n tile, fastest -> L3 reuse of A)
    const int mt = blockIdx.y;          // 0..1023
    const int tid  = threadIdx.x;
    const int lane = tid & 63;
    const int wave = tid >> 6;
    const int wm = wave >> 1, wn = wave & 1;
    const int l15 = lane & 15, q = lane >> 4;

    const int rbase = tid >> 3;         // 0..31
    const int kc    = (tid & 7) * 8;    // 0..56

    f32x4 acc[4][4] = {};

    for (int kt = 0; kt < HID / BK; ++kt) {
        const int k0 = kt * BK;
        // stage A (fp32 -> bf16) and B (already bf16)
        #pragma unroll
        for (int j = 0; j < 4; ++j) {
            const int row = rbase + j * 32;
            const float4* asrc =
                (const float4*)(x + (size_t)(mt * BM + row) * HID + k0 + kc);
            float4 a0 = asrc[0];
            float4 a1 = asrc[1];
            uint4 bsrc = *(const uint4*)(Wb + (size_t)(nt * BN + row) * HID + k0 + kc);
            ushort8v v;
            v[0] = f2bf(a0.x); v[1] = f2bf(a0.y); v[2] = f2bf(a0.z); v[3] = f2bf(a0.w);
            v[4] = f2bf(a1.x); v[5] = f2bf(a1.y); v[6] = f2bf(a1.z); v[7] = f2bf(a1.w);
            *(ushort8v*)&As[row][kc] = v;
            *(uint4*)&Bs[row][kc]    = bsrc;
        }
        __syncthreads();
        #pragma unroll
        for (int kh = 0; kh < 2; ++kh) {
            bf16x8 af[4], bf[4];
            #pragma unroll
            for (int mi = 0; mi < 4; ++mi)
                af[mi] = *(const bf16x8*)&As[wm * 64 + mi * 16 + l15][kh * 32 + q * 8];
            #pragma unroll
            for (int ni = 0; ni < 4; ++ni)
                bf[ni] = *(const bf16x8*)&Bs[wn * 64 + ni * 16 + l15][kh * 32 + q * 8];
            #pragma unroll
            for (int mi = 0; mi < 4; ++mi)
                #pragma unroll
                for (int ni = 0; ni < 4; ++ni)
                    acc[mi][ni] = __builtin_amdgcn_mfma_f32_16x16x32_bf16(
                        af[mi], bf[ni], acc[mi][ni], 0, 0, 0);
        }
        __syncthreads();
    }

    // epilogue: per-lane ctx-weighted tanh partial over this wave's 64 cols
    float ps[16];
    #pragma unroll
    for (int mi = 0; mi < 4; ++mi)
        #pragma unroll
        for (int r = 0; r < 4; ++r) {
            float s = 0.f;
            #pragma unroll
            for (int ni = 0; ni < 4; ++ni) {
                const int o = nt * BN + wn * 64 + ni * 16 + l15;
                float y = acc[mi][ni][r] + bias[o];
                s += ctx[o] * tanh_fast(y);
            }
            ps[mi * 4 + r] = s;
        }
    // reduce across the 16 cols held by lanes sharing q (xor masks < 16)
    #pragma unroll
    for (int off = 1; off < 16; off <<= 1)
        #pragma unroll
        for (int i = 0; i < 16; ++i)
            ps[i] += __shfl_xor(ps[i], off, 64);
    if (l15 == 0) {
        #pragma unroll
        for (int mi = 0; mi < 4; ++mi)
            #pragma unroll
            for (int r = 0; r < 4; ++r) {
                const int m = mt * BM + wm * 64 + mi * 16 + q * 4 + r;
                atomicAdd(&sims[m], ps[mi * 4 + r]);
            }
    }
}

// ---- kernel 3: softmax over seq, per batch -----------------------------
__global__ __launch_bounds__(256) void softmax_kernel(const float* __restrict__ sims,
                                                      float* __restrict__ probs) {
    const int b = blockIdx.x;
    const int tid = threadIdx.x;
    const int lane = tid & 63, wave = tid >> 6;
    __shared__ float red[4];

    float v[16];
    #pragma unroll
    for (int i = 0; i < 16; ++i) v[i] = sims[(size_t)(i * 256 + tid) * BATCH + b];

    float mx = -INFINITY;
    #pragma unroll
    for (int i = 0; i < 16; ++i) mx = fmaxf(mx, v[i]);
    #pragma unroll
    for (int off = 32; off >= 1; off >>= 1) mx = fmaxf(mx, __shfl_xor(mx, off, 64));
    if (lane == 0) red[wave] = mx;
    __syncthreads();
    mx = fmaxf(fmaxf(red[0], red[1]), fmaxf(red[2], red[3]));
    __syncthreads();

    float sum = 0.f;
    #pragma unroll
    for (int i = 0; i < 16; ++i) { v[i] = __expf(v[i] - mx); sum += v[i]; }
    #pragma unroll
    for (int off = 32; off >= 1; off >>= 1) sum += __shfl_xor(sum, off, 64);
    if (lane == 0) red[wave] = sum;
    __syncthreads();
    const float inv = 1.0f / (red[0] + red[1] + red[2] + red[3]);

    #pragma unroll
    for (int i = 0; i < 16; ++i)
        probs[(size_t)(i * 256 + tid) * BATCH + b] = v[i] * inv;
}

// ---- kernel 4: weighted-sum pooling ------------------------------------
__global__ __launch_bounds__(512) void attend_kernel(const float* __restrict__ x,
                                                     const float* __restrict__ probs,
                                                     float* __restrict__ out) {
    const int st = blockIdx.x;   // 0..31 (seq tile of 128)
    const int b  = blockIdx.y;   // 0..31
    const int h  = threadIdx.x;  // 0..511
    __shared__ float p[128];
    if (h < 128) p[h] = probs[(size_t)(st * 128 + h) * BATCH + b];
    __syncthreads();
    float acc = 0.f;
    const float* xp = x + ((size_t)(st * 128) * BATCH + b) * HID + h;
    #pragma unroll 4
    for (int s = 0; s < 128; ++s)
        acc += p[s] * xp[(size_t)s * BATCH * HID];
    atomicAdd(&out[b * HID + h], acc);
}

extern "C" void kernel_launch(void* const* d_in, const int* in_sizes, int n_in,
                              void* d_out, int out_size, void* d_ws, size_t ws_size,
                              hipStream_t stream) {
    const float* x    = (const float*)d_in[0];
    const float* W    = (const float*)d_in[1];
    const float* bias = (const float*)d_in[2];
    const float* ctx  = (const float*)d_in[3];
    float* out = (float*)d_out;

    unsigned short* Wb = (unsigned short*)d_ws;                        // 512 KB
    float* sims  = (float*)((char*)d_ws + (512 << 10));                // 512 KB
    float* probs = (float*)((char*)d_ws + (1024 << 10));               // 512 KB

    hipMemsetAsync(sims, 0, MTOT * sizeof(float), stream);
    hipMemsetAsync(d_out, 0, (size_t)out_size * sizeof(float), stream);

    cvt_w_kernel<<<256, 256, 0, stream>>>(W, Wb);
    gemm_sim_kernel<<<dim3(4, 1024), 256, 0, stream>>>(x, Wb, bias, ctx, sims);
    softmax_kernel<<<32, 256, 0, stream>>>(sims, probs);
    attend_kernel<<<dim3(32, 32), 512, 0, stream>>>(x, probs, out);
}